// Round 5
// baseline (528.243 us; speedup 1.0000x reference)
//
#include <hip/hip_runtime.h>

// Instant-NGP 2D hashgrid (L=16, T=2^20, F=2, N_MIN=16, b=2) + MLP 32->128->128->3.
//
// Three-pass structure:
//   Pass 0 (ngp_pack): tables f32[L][T][2] -> packed bf16 pairs u32[L][T] (64 MiB).
//     One hashed level = 4 MiB = per-XCD L2 size.
//   Pass 1 (ngp_encode): level-major grid (16 levels x bpl blocks), 8 pts/thread.
//     All 32 gather indices computed, ALL 32 loads issued as one batch,
//     sched_barrier(0), then interpolation math. Depth ladder measured:
//     8-deep=255us (r2), 16-deep=216us (r4); this round 32-deep.
//     Occupancy at VGPR=32 was already maxed (8 waves/SIMD), so added
//     in-flight depth must come from per-thread batch size.
//     NO nontemporal loads: round 3 proved nt defeats L2 retention on gfx950
//     (FETCH 320MB -> 1.12GB, dur 255 -> 523us).
//   Pass 2 (ngp_mlp): round-1-verified fused MLP (both barriers, uniform loop)
//     + register prefetch of next tile's features. Unchanged from round 4.
//
// mfma_f32_16x16x32_bf16 layouts (HW-verified per guide):
//   A[m][k]: m = lane&15, k = (lane>>4)*8 + j   (8 bf16 / lane)
//   B[k][n]: n = lane&15, k = (lane>>4)*8 + j
//   D[m][n]: n = lane&15, m = (lane>>4)*4 + r   (4 f32 / lane)

#define T_SIZE  (1u << 20)
#define HASH_Y  2654435761u
#define NLVL    16
#define MAXPTS  (1u << 20)

typedef __bf16 bf16x8 __attribute__((ext_vector_type(8)));
typedef float f32x4 __attribute__((ext_vector_type(4)));
typedef unsigned short u16x8 __attribute__((ext_vector_type(8)));
typedef unsigned short u16x4 __attribute__((ext_vector_type(4)));

// 64 MiB packed-bf16 table + 64 MiB feature scratch.
__device__ unsigned int g_tbl[NLVL * T_SIZE];
__device__ unsigned int g_feat[NLVL * MAXPTS];

static __device__ __forceinline__ unsigned short f2bf(float f) {
    union { float f; unsigned u; } v; v.f = f;
    unsigned u = v.u;
    u += 0x7fffu + ((u >> 16) & 1u);   // round-to-nearest-even
    return (unsigned short)(u >> 16);
}

static __device__ __forceinline__ unsigned packbf(float a, float b) {
    return (unsigned)f2bf(a) | ((unsigned)f2bf(b) << 16);
}

static __device__ __forceinline__ float bflo(unsigned p) {
    union { unsigned u; float f; } v; v.u = p << 16; return v.f;
}
static __device__ __forceinline__ float bfhi(unsigned p) {
    union { unsigned u; float f; } v; v.u = p & 0xffff0000u; return v.f;
}

static __device__ __forceinline__ f32x4 mfma16(u16x8 a, u16x8 b, f32x4 c) {
    return __builtin_amdgcn_mfma_f32_16x16x32_bf16(
        __builtin_bit_cast(bf16x8, a), __builtin_bit_cast(bf16x8, b), c, 0, 0, 0);
}

// ---------------- Pass 0: pack tables to bf16 pairs ----------------
// 16M entries; each thread packs 4 (2x float4 in, 1x uint4 out).
__global__ __launch_bounds__(256)
void ngp_pack(const float* __restrict__ tables)
{
    unsigned i = (blockIdx.x * 256u + threadIdx.x) * 4u;   // entry index
    const float4* s = (const float4*)(tables + (size_t)i * 2);
    float4 a = s[0], b = s[1];
    uint4 o;
    o.x = packbf(a.x, a.y);
    o.y = packbf(a.z, a.w);
    o.z = packbf(b.x, b.y);
    o.w = packbf(b.z, b.w);
    *(uint4*)(g_tbl + i) = o;
}

// ---------------- Pass 1: level-major hashgrid encode ----------------
// blockIdx = lvl * bpl + blk; each block encodes 2048 consecutive points at
// one level; each thread does 8 consecutive points (2x uint4 feature store).
__global__ __launch_bounds__(256)
void ngp_encode(const float* __restrict__ uv, int npts, int bpl)
{
    const int bid = blockIdx.x;
    const int lvl = bid / bpl;               // scalar div, once per block
    const int blk = bid - lvl * bpl;
    const int base = (blk << 11) + (threadIdx.x << 3);
    if (base >= npts) return;

    const unsigned res = 16u << lvl;
    const float fres = (float)res;
    const unsigned rp1 = res + 1u;
    const unsigned mask = T_SIZE - 1u;
    const bool dense = lvl < 6;              // (res+1)^2 <= T  <=>  lvl <= 5
    const unsigned* __restrict__ tl = g_tbl + (size_t)lvl * T_SIZE;

    // uv for 8 consecutive points: 64 B, four float4 loads.
    const float4* u4 = (const float4*)(uv + (size_t)base * 2);
    float4 ua = u4[0], ub = u4[1], uc = u4[2], ud = u4[3];
    float pxa[8] = {ua.x, ua.z, ub.x, ub.z, uc.x, uc.z, ud.x, ud.z};
    float pya[8] = {ua.y, ua.w, ub.y, ub.w, uc.y, uc.w, ud.y, ud.w};

    // Phase A: all 32 indices + weights.
    unsigned i00[8], i01[8], i10[8], i11[8];
    float wx[8], wy[8];
#pragma unroll
    for (int u = 0; u < 8; ++u) {
        float px = pxa[u] * fres, py = pya[u] * fres;
        float fx = floorf(px), fy = floorf(py);
        wx[u] = px - fx; wy[u] = py - fy;
        unsigned cx = (unsigned)fx, cy = (unsigned)fy;
        unsigned hy0 = cy * HASH_Y, hy1 = (cy + 1u) * HASH_Y;
        i00[u] = dense ? (cx + cy * rp1)              : ((cx ^ hy0) & mask);
        i01[u] = dense ? (cx + (cy + 1u) * rp1)       : ((cx ^ hy1) & mask);
        i10[u] = dense ? (cx + 1u + cy * rp1)         : (((cx + 1u) ^ hy0) & mask);
        i11[u] = dense ? (cx + 1u + (cy + 1u) * rp1)  : (((cx + 1u) ^ hy1) & mask);
    }
    // Phase B: all 32 gathers issued as ONE batch; sched_barrier keeps the
    // interpolation math out of the load stream so all 32 stay in flight.
    unsigned e00[8], e01[8], e10[8], e11[8];
#pragma unroll
    for (int u = 0; u < 8; ++u) {
        e00[u] = tl[i00[u]];
        e01[u] = tl[i01[u]];
        e10[u] = tl[i10[u]];
        e11[u] = tl[i11[u]];
    }
    __builtin_amdgcn_sched_barrier(0);
    // Phase C: bilinear interp + pack.
    unsigned pk[8];
#pragma unroll
    for (int u = 0; u < 8; ++u) {
        float w00 = (1.f - wx[u]) * (1.f - wy[u]);
        float w01 = (1.f - wx[u]) * wy[u];
        float w10 = wx[u] * (1.f - wy[u]);
        float w11 = wx[u] * wy[u];
        float g0 = w00 * bflo(e00[u]) + w01 * bflo(e01[u]) + w10 * bflo(e10[u]) + w11 * bflo(e11[u]);
        float g1 = w00 * bfhi(e00[u]) + w01 * bfhi(e01[u]) + w10 * bfhi(e10[u]) + w11 * bfhi(e11[u]);
        pk[u] = packbf(g0, g1);
    }
    unsigned* fp = g_feat + (size_t)lvl * npts + base;
    *(uint4*)(fp)     = make_uint4(pk[0], pk[1], pk[2], pk[3]);
    *(uint4*)(fp + 4) = make_uint4(pk[4], pk[5], pk[6], pk[7]);
}

// ---------------- Pass 2: fused MLP 32->128->128->3 ----------------
// LDS: w2T[out 128][in 136 pad] bf16 (34816 B) + h[4 waves][16 pts][136 pad]
// (17408 B) + biases (1024 B) = 53248 B; ~3 blocks/CU by LDS.
// Round-1-verified structure (both barriers, uniform niter loop); single
// delta: next tile's features prefetched into registers during compute.
__global__ __launch_bounds__(256, 2)
void ngp_mlp(const float* __restrict__ w1, const float* __restrict__ b1,
             const float* __restrict__ w2, const float* __restrict__ b2,
             const float* __restrict__ w3, const float* __restrict__ b3,
             float* __restrict__ out, int npts)
{
    __shared__ __align__(16) unsigned short w2T[128 * 136];
    __shared__ __align__(16) unsigned short hbuf[4 * 16 * 136];
    __shared__ float b1s[128], b2s[128];

    const int tid = threadIdx.x;
    for (int e = tid; e < 128 * 128; e += 256) {        // w2 is [in][out]; store w2T[out][in]
        int i = e >> 7, o = e & 127;
        w2T[o * 136 + i] = f2bf(w2[e]);
    }
    if (tid < 128) { b1s[tid] = b1[tid]; b2s[tid] = b2[tid]; }
    __syncthreads();

    const int lane = tid & 63;
    const int wv = tid >> 6;
    const int lanelo = lane & 15;
    const int quad = lane >> 4;

    // Register-resident A-fragments: layer 1 (w1^T [128x32]) and layer 3 (w3^T [3x128], rows 3..15 zero).
    u16x8 a1[8];
#pragma unroll
    for (int mt = 0; mt < 8; ++mt)
#pragma unroll
        for (int j = 0; j < 8; ++j)
            a1[mt][j] = f2bf(w1[(quad * 8 + j) * 128 + mt * 16 + lanelo]);  // w1[k][m]

    u16x8 a3[4];
#pragma unroll
    for (int ks = 0; ks < 4; ++ks)
#pragma unroll
        for (int j = 0; j < 8; ++j) {
            int k = ks * 32 + quad * 8 + j;
            a3[ks][j] = (lanelo < 3) ? f2bf(w3[k * 3 + lanelo]) : (unsigned short)0;  // w3[k][m]
        }
    float b3r0 = b3[0], b3r1 = b3[1], b3r2 = b3[2];

    const int NT = npts >> 4;                 // 16-point tiles
    const int nwaves = gridDim.x * 4;
    const int gwave = blockIdx.x * 4 + wv;
    const int niter = (NT + nwaves - 1) / nwaves;   // uniform trip count (syncthreads-safe)

    unsigned short* hp = hbuf + (wv * 16 + lanelo) * 136;   // this lane's point-row
    const int lvlbase = quad << 2;            // this lane's 4 levels

    // Preload iter-0 features.
    unsigned c0 = 0, c1 = 0, c2 = 0, c3 = 0;
    if (gwave < NT) {
        int pt0 = (gwave << 4) + lanelo;
        c0 = g_feat[(size_t)(lvlbase + 0) * npts + pt0];
        c1 = g_feat[(size_t)(lvlbase + 1) * npts + pt0];
        c2 = g_feat[(size_t)(lvlbase + 2) * npts + pt0];
        c3 = g_feat[(size_t)(lvlbase + 3) * npts + pt0];
    }

    for (int it = 0; it < niter; ++it) {
        int tile = gwave + it * nwaves;
        bool act = tile < NT;
        int pt = (tile << 4) + lanelo;

        if (act) {
            // ---- B-fragment from (pre)loaded feats ----
            u16x8 xb;
            xb[0] = (unsigned short)(c0 & 0xffffu); xb[1] = (unsigned short)(c0 >> 16);
            xb[2] = (unsigned short)(c1 & 0xffffu); xb[3] = (unsigned short)(c1 >> 16);
            xb[4] = (unsigned short)(c2 & 0xffffu); xb[5] = (unsigned short)(c2 >> 16);
            xb[6] = (unsigned short)(c3 & 0xffffu); xb[7] = (unsigned short)(c3 >> 16);

            // ---- prefetch next tile's feats (latency hidden under MFMA/LDS/barriers) ----
            int tn = tile + nwaves;
            if (tn < NT) {
                int ptn = (tn << 4) + lanelo;
                c0 = g_feat[(size_t)(lvlbase + 0) * npts + ptn];
                c1 = g_feat[(size_t)(lvlbase + 1) * npts + ptn];
                c2 = g_feat[(size_t)(lvlbase + 2) * npts + ptn];
                c3 = g_feat[(size_t)(lvlbase + 3) * npts + ptn];
            }

            // ---- layer 1: 8 MFMAs, K=32 in one shot ----
            f32x4 z = {0.f, 0.f, 0.f, 0.f};
            f32x4 d[8];
#pragma unroll
            for (int mt = 0; mt < 8; ++mt) d[mt] = mfma16(a1[mt], xb, z);
#pragma unroll
            for (int mt = 0; mt < 8; ++mt) {
                u16x4 pk;
#pragma unroll
                for (int r = 0; r < 4; ++r) {
                    float hv = d[mt][r] + b1s[mt * 16 + quad * 4 + r];
                    pk[r] = f2bf(fmaxf(hv, 0.f));
                }
                *(u16x4*)(hp + mt * 16 + quad * 4) = pk;
            }
        }
        __syncthreads();
        if (act) {
            // ---- layer 2: K=128 in 4 steps x 8 m-tiles ----
            f32x4 z = {0.f, 0.f, 0.f, 0.f};
            f32x4 e[8];
#pragma unroll
            for (int mt = 0; mt < 8; ++mt) e[mt] = z;
#pragma unroll
            for (int ks = 0; ks < 4; ++ks) {
                u16x8 bb = *(const u16x8*)(hp + ks * 32 + quad * 8);   // h1[pt][k..k+7]
#pragma unroll
                for (int mt = 0; mt < 8; ++mt) {
                    u16x8 aa = *(const u16x8*)(w2T + (mt * 16 + lanelo) * 136 + ks * 32 + quad * 8);
                    e[mt] = mfma16(aa, bb, e[mt]);
                }
            }
            // bias + relu + pack back to same LDS rows (all reads above precede these writes; DS in-order per wave)
#pragma unroll
            for (int mt = 0; mt < 8; ++mt) {
                u16x4 pk;
#pragma unroll
                for (int r = 0; r < 4; ++r) {
                    float hv = e[mt][r] + b2s[mt * 16 + quad * 4 + r];
                    pk[r] = f2bf(fmaxf(hv, 0.f));
                }
                *(u16x4*)(hp + mt * 16 + quad * 4) = pk;
            }
        }
        __syncthreads();
        if (act) {
            // ---- layer 3: 4 MFMAs, rows 0..2 = RGB logits ----
            f32x4 o3 = {0.f, 0.f, 0.f, 0.f};
#pragma unroll
            for (int ks = 0; ks < 4; ++ks) {
                u16x8 bb = *(const u16x8*)(hp + ks * 32 + quad * 8);
                o3 = mfma16(a3[ks], bb, o3);
            }
            if (quad == 0) {   // D rows quad*4+r -> rows 0..2 live in quad 0
                float* op = out + (size_t)pt * 3;
                op[0] = 1.f / (1.f + expf(-(o3[0] + b3r0)));
                op[1] = 1.f / (1.f + expf(-(o3[1] + b3r1)));
                op[2] = 1.f / (1.f + expf(-(o3[2] + b3r2)));
            }
        }
    }
}

extern "C" void kernel_launch(void* const* d_in, const int* in_sizes, int n_in,
                              void* d_out, int out_size, void* d_ws, size_t ws_size,
                              hipStream_t stream) {
    const float* uv     = (const float*)d_in[0];
    const float* tables = (const float*)d_in[1];
    const float* w1     = (const float*)d_in[2];
    const float* b1     = (const float*)d_in[3];
    const float* w2     = (const float*)d_in[4];
    const float* b2     = (const float*)d_in[5];
    const float* w3     = (const float*)d_in[6];
    const float* b3     = (const float*)d_in[7];
    float* out = (float*)d_out;
    int npts = in_sizes[0] / 2;          // uv is [N,2]

    // Pass 0: bf16-pack all 16M table entries. 16384 blocks x 256 thr x 4 entries.
    hipLaunchKernelGGL(ngp_pack, dim3((NLVL * T_SIZE) / 1024), dim3(256), 0, stream,
                       tables);

    // Pass 1: level-major encode. bpl blocks of 2048 points per level.
    int bpl = (npts + 2047) >> 11;
    hipLaunchKernelGGL(ngp_encode, dim3(NLVL * bpl), dim3(256), 0, stream,
                       uv, npts, bpl);

    // Pass 2: fused MLP. 2048 blocks x 4 waves = 8192 wave-slots.
    hipLaunchKernelGGL(ngp_mlp, dim3(2048), dim3(256), 0, stream,
                       w1, b1, w2, b2, w3, b3, out, npts);
}

// Round 6
// 500.773 us; speedup vs baseline: 1.0549x; 1.0549x over previous
//
#include <hip/hip_runtime.h>

// Instant-NGP 2D hashgrid (L=16, T=2^20, F=2, N_MIN=16, b=2) + MLP 32->128->128->3.
//
// Four-kernel structure:
//   Pass 0a (ngp_pack): hashed levels 6..15 f32[T][2] -> packed bf16 u32[T].
//   Pass 0b (ngp_dense): dense levels 0..5 -> duplicated-pair table
//     dp[cy*rp1+cx] = (pack(t[cx,cy]), pack(t[cx+1,cy]))  (2.8 MiB total).
//     One aligned uint2 load yields BOTH x-corners of a row.
//   Pass 1 (ngp_encode): level-major grid, 4 pts/thread.
//     r5 established the gather path saturates at ~128 in-flight lane-requests
//     per SIMD (~0.5 req/cyc/CU): THROUGHPUT-bound on request count, not
//     latency. So this round cuts requests 34%:
//       dense: 2 pair-loads/pt-level (was 4)   [dp table]
//       hashed: XOR-hash gives slot(cx^1)=slot(cx)^1, so even-cx corners are
//         one aligned uint2; odd-cx needs a 2nd exec-masked load. avg 3 (was 4).
//     Masked pair-1 loads land in separate regs (merged by cndmask after the
//     sched_barrier) so no waitcnt interrupts the load batch.
//     NO nontemporal (r3: nt defeats L2 retention: FETCH 320MB->1.12GB).
//   Pass 2 (ngp_mlp): round-4-verified fused MLP, byte-identical.
//
// mfma_f32_16x16x32_bf16 layouts (HW-verified per guide):
//   A[m][k]: m = lane&15, k = (lane>>4)*8 + j   (8 bf16 / lane)
//   B[k][n]: n = lane&15, k = (lane>>4)*8 + j
//   D[m][n]: n = lane&15, m = (lane>>4)*4 + r   (4 f32 / lane)

#define T_SIZE  (1u << 20)
#define HASH_Y  2654435761u
#define NLVL    16
#define MAXPTS  (1u << 20)
#define DP_TOTAL 351462   // sum of (16*2^l+1)^2 for l=0..5

typedef __bf16 bf16x8 __attribute__((ext_vector_type(8)));
typedef float f32x4 __attribute__((ext_vector_type(4)));
typedef unsigned short u16x8 __attribute__((ext_vector_type(8)));
typedef unsigned short u16x4 __attribute__((ext_vector_type(4)));

__constant__ int DP_OFF[7] = {0, 289, 1378, 5603, 22244, 88293, DP_TOTAL};

// packed-bf16 hashed tables (levels 6..15 used) + dense pair table + features.
__device__ unsigned int g_tbl[NLVL * T_SIZE];
__device__ uint2        g_dp[DP_TOTAL];
__device__ unsigned int g_feat[NLVL * MAXPTS];

static __device__ __forceinline__ unsigned short f2bf(float f) {
    union { float f; unsigned u; } v; v.f = f;
    unsigned u = v.u;
    u += 0x7fffu + ((u >> 16) & 1u);   // round-to-nearest-even
    return (unsigned short)(u >> 16);
}

static __device__ __forceinline__ unsigned packbf(float a, float b) {
    return (unsigned)f2bf(a) | ((unsigned)f2bf(b) << 16);
}

static __device__ __forceinline__ float bflo(unsigned p) {
    union { unsigned u; float f; } v; v.u = p << 16; return v.f;
}
static __device__ __forceinline__ float bfhi(unsigned p) {
    union { unsigned u; float f; } v; v.u = p & 0xffff0000u; return v.f;
}

static __device__ __forceinline__ f32x4 mfma16(u16x8 a, u16x8 b, f32x4 c) {
    return __builtin_amdgcn_mfma_f32_16x16x32_bf16(
        __builtin_bit_cast(bf16x8, a), __builtin_bit_cast(bf16x8, b), c, 0, 0, 0);
}

// ---------------- Pass 0a: pack hashed tables to bf16 pairs ----------------
// Levels 6..15: 10M entries; each thread packs 4.
__global__ __launch_bounds__(256)
void ngp_pack(const float* __restrict__ tables)
{
    unsigned i = 6u * T_SIZE + (blockIdx.x * 256u + threadIdx.x) * 4u;
    const float4* s = (const float4*)(tables + (size_t)i * 2);
    float4 a = s[0], b = s[1];
    uint4 o;
    o.x = packbf(a.x, a.y);
    o.y = packbf(a.z, a.w);
    o.z = packbf(b.x, b.y);
    o.w = packbf(b.z, b.w);
    *(uint4*)(g_tbl + i) = o;
}

// ---------------- Pass 0b: dense duplicated-pair table ----------------
__global__ __launch_bounds__(256)
void ngp_dense(const float* __restrict__ tables)
{
    int idx = blockIdx.x * 256 + threadIdx.x;
    if (idx >= DP_TOTAL) return;
    int lvl = 0;
#pragma unroll
    for (int l = 1; l < 6; ++l) if (idx >= DP_OFF[l]) lvl = l;
    int loc = idx - DP_OFF[lvl];
    unsigned rp1 = (16u << lvl) + 1u;
    unsigned cy = (unsigned)loc / rp1;
    unsigned cx = (unsigned)loc - cy * rp1;
    const float2* t2 = (const float2*)tables + (size_t)lvl * T_SIZE;
    float2 a = t2[cy * rp1 + cx];
    unsigned cx1 = (cx + 1u < rp1) ? cx + 1u : cx;
    float2 b = t2[cy * rp1 + cx1];
    g_dp[idx] = make_uint2(packbf(a.x, a.y), packbf(b.x, b.y));
}

// ---------------- Pass 1: level-major hashgrid encode ----------------
// blockIdx = lvl * bpl + blk; 1024 points/block, 4 points/thread.
__global__ __launch_bounds__(256, 6)
void ngp_encode(const float* __restrict__ uv, int npts, int bpl)
{
    const int bid = blockIdx.x;
    const int lvl = bid / bpl;
    const int blk = bid - lvl * bpl;
    const int base = (blk << 10) + (threadIdx.x << 2);
    if (base >= npts) return;

    const unsigned res = 16u << lvl;
    const float fres = (float)res;
    const unsigned mask = T_SIZE - 1u;

    // uv for 4 consecutive points.
    const float4* u4 = (const float4*)(uv + (size_t)base * 2);
    float4 ua = u4[0], ub = u4[1];
    float pxa[4] = {ua.x, ua.z, ub.x, ub.z};
    float pya[4] = {ua.y, ua.w, ub.y, ub.w};

    float wx[4], wy[4];
    unsigned v00[4], v10[4], v01[4], v11[4];   // packed bf16 corner values

    if (lvl < 6) {
        // ---- dense: pair table, 2 loads/pt ----
        const unsigned rp1 = res + 1u;
        const uint2* __restrict__ dp = g_dp + DP_OFF[lvl];
        unsigned i0[4];
#pragma unroll
        for (int u = 0; u < 4; ++u) {
            float px = pxa[u] * fres, py = pya[u] * fres;
            float fx = floorf(px), fy = floorf(py);
            wx[u] = px - fx; wy[u] = py - fy;
            unsigned cx = (unsigned)fx, cy = (unsigned)fy;
            i0[u] = cy * rp1 + cx;
        }
        uint2 q0[4], q1[4];
#pragma unroll
        for (int u = 0; u < 4; ++u) {
            q0[u] = dp[i0[u]];
            q1[u] = dp[i0[u] + rp1];
        }
        __builtin_amdgcn_sched_barrier(0);
#pragma unroll
        for (int u = 0; u < 4; ++u) {
            v00[u] = q0[u].x; v10[u] = q0[u].y;
            v01[u] = q1[u].x; v11[u] = q1[u].y;
        }
    } else {
        // ---- hashed: even-x pair loads via xor-adjacency ----
        const unsigned* __restrict__ tl = g_tbl + (size_t)lvl * T_SIZE;
        unsigned p00[4], p01[4], p10[4], p11[4], oddb[4], c0b[4];
#pragma unroll
        for (int u = 0; u < 4; ++u) {
            float px = pxa[u] * fres, py = pya[u] * fres;
            float fx = floorf(px), fy = floorf(py);
            wx[u] = px - fx; wy[u] = py - fy;
            unsigned cx = (unsigned)fx, cy = (unsigned)fy;
            unsigned odd = cx & 1u;
            unsigned cxe = cx & ~1u;
            unsigned cxn = (cx + 1u) & ~1u;          // next even coord (== cxe when cx even; masked off)
            unsigned hy0 = cy * HASH_Y, hy1 = hy0 + HASH_Y;
            p00[u] = ((cxe ^ hy0) & mask) & ~1u;
            p01[u] = ((cxe ^ hy1) & mask) & ~1u;
            p10[u] = ((cxn ^ hy0) & mask) & ~1u;
            p11[u] = ((cxn ^ hy1) & mask) & ~1u;
            oddb[u] = odd;
            c0b[u] = cy & 1u;
        }
        // Unconditional pair-0 loads (8), then exec-masked pair-1 loads
        // (odd-cx lanes only -> avg 4 more; masked lanes cost no TA requests).
        uint2 q00[4], q01[4], r10[4], r11[4];
#pragma unroll
        for (int u = 0; u < 4; ++u) {
            q00[u] = *(const uint2*)(tl + p00[u]);
            q01[u] = *(const uint2*)(tl + p01[u]);
            r10[u] = make_uint2(0u, 0u);
            r11[u] = make_uint2(0u, 0u);
        }
#pragma unroll
        for (int u = 0; u < 4; ++u) {
            if (oddb[u]) {
                r10[u] = *(const uint2*)(tl + p10[u]);
                r11[u] = *(const uint2*)(tl + p11[u]);
            }
        }
        __builtin_amdgcn_sched_barrier(0);
        // Merge: slot(coord c) has bit0 = parity(c)^parity(hy); corner cxe is
        // at p+ (cy&1), corner cxe+1 at p + ((cy&1)^1). For odd cx the right
        // corner comes from the pair-1 load (index cy&1 on row0).
#pragma unroll
        for (int u = 0; u < 4; ++u) {
            unsigned c0 = c0b[u], od = oddb[u];
            unsigned sL0 = c0 ^ od;
            unsigned c1 = c0 ^ 1u;
            unsigned sL1 = c1 ^ od;
            uint2 h10 = od ? r10[u] : q00[u];
            uint2 h11 = od ? r11[u] : q01[u];
            v00[u] = sL0 ? q00[u].y : q00[u].x;
            v10[u] = sL0 ? h10.x   : h10.y;      // index sL0^1
            v01[u] = sL1 ? q01[u].y : q01[u].x;
            v11[u] = sL1 ? h11.x   : h11.y;      // index sL1^1
        }
    }

    // ---- bilinear interp + pack ----
    unsigned pk[4];
#pragma unroll
    for (int u = 0; u < 4; ++u) {
        float w00 = (1.f - wx[u]) * (1.f - wy[u]);
        float w01 = (1.f - wx[u]) * wy[u];
        float w10 = wx[u] * (1.f - wy[u]);
        float w11 = wx[u] * wy[u];
        float g0 = w00 * bflo(v00[u]) + w01 * bflo(v01[u]) + w10 * bflo(v10[u]) + w11 * bflo(v11[u]);
        float g1 = w00 * bfhi(v00[u]) + w01 * bfhi(v01[u]) + w10 * bfhi(v10[u]) + w11 * bfhi(v11[u]);
        pk[u] = packbf(g0, g1);
    }
    *(uint4*)(g_feat + (size_t)lvl * npts + base) = make_uint4(pk[0], pk[1], pk[2], pk[3]);
}

// ---------------- Pass 2: fused MLP 32->128->128->3 (round-4 verified) ----------------
__global__ __launch_bounds__(256, 2)
void ngp_mlp(const float* __restrict__ w1, const float* __restrict__ b1,
             const float* __restrict__ w2, const float* __restrict__ b2,
             const float* __restrict__ w3, const float* __restrict__ b3,
             float* __restrict__ out, int npts)
{
    __shared__ __align__(16) unsigned short w2T[128 * 136];
    __shared__ __align__(16) unsigned short hbuf[4 * 16 * 136];
    __shared__ float b1s[128], b2s[128];

    const int tid = threadIdx.x;
    for (int e = tid; e < 128 * 128; e += 256) {        // w2 is [in][out]; store w2T[out][in]
        int i = e >> 7, o = e & 127;
        w2T[o * 136 + i] = f2bf(w2[e]);
    }
    if (tid < 128) { b1s[tid] = b1[tid]; b2s[tid] = b2[tid]; }
    __syncthreads();

    const int lane = tid & 63;
    const int wv = tid >> 6;
    const int lanelo = lane & 15;
    const int quad = lane >> 4;

    u16x8 a1[8];
#pragma unroll
    for (int mt = 0; mt < 8; ++mt)
#pragma unroll
        for (int j = 0; j < 8; ++j)
            a1[mt][j] = f2bf(w1[(quad * 8 + j) * 128 + mt * 16 + lanelo]);  // w1[k][m]

    u16x8 a3[4];
#pragma unroll
    for (int ks = 0; ks < 4; ++ks)
#pragma unroll
        for (int j = 0; j < 8; ++j) {
            int k = ks * 32 + quad * 8 + j;
            a3[ks][j] = (lanelo < 3) ? f2bf(w3[k * 3 + lanelo]) : (unsigned short)0;  // w3[k][m]
        }
    float b3r0 = b3[0], b3r1 = b3[1], b3r2 = b3[2];

    const int NT = npts >> 4;                 // 16-point tiles
    const int nwaves = gridDim.x * 4;
    const int gwave = blockIdx.x * 4 + wv;
    const int niter = (NT + nwaves - 1) / nwaves;   // uniform trip count (syncthreads-safe)

    unsigned short* hp = hbuf + (wv * 16 + lanelo) * 136;   // this lane's point-row
    const int lvlbase = quad << 2;            // this lane's 4 levels

    unsigned c0 = 0, c1 = 0, c2 = 0, c3 = 0;
    if (gwave < NT) {
        int pt0 = (gwave << 4) + lanelo;
        c0 = g_feat[(size_t)(lvlbase + 0) * npts + pt0];
        c1 = g_feat[(size_t)(lvlbase + 1) * npts + pt0];
        c2 = g_feat[(size_t)(lvlbase + 2) * npts + pt0];
        c3 = g_feat[(size_t)(lvlbase + 3) * npts + pt0];
    }

    for (int it = 0; it < niter; ++it) {
        int tile = gwave + it * nwaves;
        bool act = tile < NT;
        int pt = (tile << 4) + lanelo;

        if (act) {
            u16x8 xb;
            xb[0] = (unsigned short)(c0 & 0xffffu); xb[1] = (unsigned short)(c0 >> 16);
            xb[2] = (unsigned short)(c1 & 0xffffu); xb[3] = (unsigned short)(c1 >> 16);
            xb[4] = (unsigned short)(c2 & 0xffffu); xb[5] = (unsigned short)(c2 >> 16);
            xb[6] = (unsigned short)(c3 & 0xffffu); xb[7] = (unsigned short)(c3 >> 16);

            int tn = tile + nwaves;
            if (tn < NT) {
                int ptn = (tn << 4) + lanelo;
                c0 = g_feat[(size_t)(lvlbase + 0) * npts + ptn];
                c1 = g_feat[(size_t)(lvlbase + 1) * npts + ptn];
                c2 = g_feat[(size_t)(lvlbase + 2) * npts + ptn];
                c3 = g_feat[(size_t)(lvlbase + 3) * npts + ptn];
            }

            f32x4 z = {0.f, 0.f, 0.f, 0.f};
            f32x4 d[8];
#pragma unroll
            for (int mt = 0; mt < 8; ++mt) d[mt] = mfma16(a1[mt], xb, z);
#pragma unroll
            for (int mt = 0; mt < 8; ++mt) {
                u16x4 pk;
#pragma unroll
                for (int r = 0; r < 4; ++r) {
                    float hv = d[mt][r] + b1s[mt * 16 + quad * 4 + r];
                    pk[r] = f2bf(fmaxf(hv, 0.f));
                }
                *(u16x4*)(hp + mt * 16 + quad * 4) = pk;
            }
        }
        __syncthreads();
        if (act) {
            f32x4 z = {0.f, 0.f, 0.f, 0.f};
            f32x4 e[8];
#pragma unroll
            for (int mt = 0; mt < 8; ++mt) e[mt] = z;
#pragma unroll
            for (int ks = 0; ks < 4; ++ks) {
                u16x8 bb = *(const u16x8*)(hp + ks * 32 + quad * 8);   // h1[pt][k..k+7]
#pragma unroll
                for (int mt = 0; mt < 8; ++mt) {
                    u16x8 aa = *(const u16x8*)(w2T + (mt * 16 + lanelo) * 136 + ks * 32 + quad * 8);
                    e[mt] = mfma16(aa, bb, e[mt]);
                }
            }
#pragma unroll
            for (int mt = 0; mt < 8; ++mt) {
                u16x4 pk;
#pragma unroll
                for (int r = 0; r < 4; ++r) {
                    float hv = e[mt][r] + b2s[mt * 16 + quad * 4 + r];
                    pk[r] = f2bf(fmaxf(hv, 0.f));
                }
                *(u16x4*)(hp + mt * 16 + quad * 4) = pk;
            }
        }
        __syncthreads();
        if (act) {
            f32x4 o3 = {0.f, 0.f, 0.f, 0.f};
#pragma unroll
            for (int ks = 0; ks < 4; ++ks) {
                u16x8 bb = *(const u16x8*)(hp + ks * 32 + quad * 8);
                o3 = mfma16(a3[ks], bb, o3);
            }
            if (quad == 0) {   // D rows quad*4+r -> rows 0..2 live in quad 0
                float* op = out + (size_t)pt * 3;
                op[0] = 1.f / (1.f + expf(-(o3[0] + b3r0)));
                op[1] = 1.f / (1.f + expf(-(o3[1] + b3r1)));
                op[2] = 1.f / (1.f + expf(-(o3[2] + b3r2)));
            }
        }
    }
}

extern "C" void kernel_launch(void* const* d_in, const int* in_sizes, int n_in,
                              void* d_out, int out_size, void* d_ws, size_t ws_size,
                              hipStream_t stream) {
    const float* uv     = (const float*)d_in[0];
    const float* tables = (const float*)d_in[1];
    const float* w1     = (const float*)d_in[2];
    const float* b1     = (const float*)d_in[3];
    const float* w2     = (const float*)d_in[4];
    const float* b2     = (const float*)d_in[5];
    const float* w3     = (const float*)d_in[6];
    const float* b3     = (const float*)d_in[7];
    float* out = (float*)d_out;
    int npts = in_sizes[0] / 2;          // uv is [N,2]

    // Pass 0a: bf16-pack hashed levels 6..15 (10M entries, 4/thread).
    hipLaunchKernelGGL(ngp_pack, dim3((10u * T_SIZE) / 1024), dim3(256), 0, stream,
                       tables);
    // Pass 0b: dense duplicated-pair table (351462 entries).
    hipLaunchKernelGGL(ngp_dense, dim3((DP_TOTAL + 255) / 256), dim3(256), 0, stream,
                       tables);

    // Pass 1: level-major encode. bpl blocks of 1024 points per level.
    int bpl = (npts + 1023) >> 10;
    hipLaunchKernelGGL(ngp_encode, dim3(NLVL * bpl), dim3(256), 0, stream,
                       uv, npts, bpl);

    // Pass 2: fused MLP. 2048 blocks x 4 waves = 8192 wave-slots.
    hipLaunchKernelGGL(ngp_mlp, dim3(2048), dim3(256), 0, stream,
                       w1, b1, w2, b2, w3, b3, out, npts);
}

// Round 8
// 498.526 us; speedup vs baseline: 1.0596x; 1.0045x over previous
//
#include <hip/hip_runtime.h>

// Instant-NGP 2D hashgrid (L=16, T=2^20, F=2, N_MIN=16, b=2) + MLP 32->128->128->3.
//
// Four-kernel structure:
//   Pass 0a (ngp_pack): hashed levels 6..15 f32[T][2] -> packed bf16 u32[T].
//   Pass 0b (ngp_dense): dense levels 0..5 -> duplicated-pair table
//     dp[cy*rp1+cx] = (pack(t[cx,cy]), pack(t[cx+1,cy]))  (2.8 MiB total).
//   Pass 1 (ngp_encode): level-major grid, 4 pts/thread.
//     History: r4 216us (16 gathers/thread), r5 223us (32 deep, occupancy
//     halved -> rate unchanged => NOT latency-depth-bound), r6 205us
//     (-34% requests -> only -5% => NOT request-count-bound).
//     Surviving theory: L1 MSHR occupancy x L2 latency caps line-fill rate
//     (~0.45 lane-req/cyc/CU invariant). This round: hashed gathers use
//     buffer_load sc0 (GLC) = bypass L1 allocation, serve from L2, KEEP L2
//     retention (r3 proved nt kills L2: FETCH 320MB->1.12GB -> reverted).
//     FETCH_SIZE is the tripwire: must stay ~400MB.
//     (r7 fix: rsrc must be __amdgpu_buffer_rsrc_t via make_buffer_rsrc,
//      not a hand-packed i32x4.)
//   Pass 2 (ngp_mlp): round-4-verified fused MLP, byte-identical.
//
// mfma_f32_16x16x32_bf16 layouts (HW-verified per guide):
//   A[m][k]: m = lane&15, k = (lane>>4)*8 + j   (8 bf16 / lane)
//   B[k][n]: n = lane&15, k = (lane>>4)*8 + j
//   D[m][n]: n = lane&15, m = (lane>>4)*4 + r   (4 f32 / lane)

#define T_SIZE  (1u << 20)
#define HASH_Y  2654435761u
#define NLVL    16
#define MAXPTS  (1u << 20)
#define DP_TOTAL 351462   // sum of (16*2^l+1)^2 for l=0..5

typedef __bf16 bf16x8 __attribute__((ext_vector_type(8)));
typedef float f32x4 __attribute__((ext_vector_type(4)));
typedef unsigned short u16x8 __attribute__((ext_vector_type(8)));
typedef unsigned short u16x4 __attribute__((ext_vector_type(4)));

__constant__ int DP_OFF[7] = {0, 289, 1378, 5603, 22244, 88293, DP_TOTAL};

// packed-bf16 hashed tables (levels 6..15 used) + dense pair table + features.
__device__ unsigned int g_tbl[NLVL * T_SIZE];
__device__ uint2        g_dp[DP_TOTAL];
__device__ unsigned int g_feat[NLVL * MAXPTS];

static __device__ __forceinline__ unsigned short f2bf(float f) {
    union { float f; unsigned u; } v; v.f = f;
    unsigned u = v.u;
    u += 0x7fffu + ((u >> 16) & 1u);   // round-to-nearest-even
    return (unsigned short)(u >> 16);
}

static __device__ __forceinline__ unsigned packbf(float a, float b) {
    return (unsigned)f2bf(a) | ((unsigned)f2bf(b) << 16);
}

static __device__ __forceinline__ float bflo(unsigned p) {
    union { unsigned u; float f; } v; v.u = p << 16; return v.f;
}
static __device__ __forceinline__ float bfhi(unsigned p) {
    union { unsigned u; float f; } v; v.u = p & 0xffff0000u; return v.f;
}

static __device__ __forceinline__ f32x4 mfma16(u16x8 a, u16x8 b, f32x4 c) {
    return __builtin_amdgcn_mfma_f32_16x16x32_bf16(
        __builtin_bit_cast(bf16x8, a), __builtin_bit_cast(bf16x8, b), c, 0, 0, 0);
}

#if __has_builtin(__builtin_amdgcn_raw_buffer_load_b64) && __has_builtin(__builtin_amdgcn_make_buffer_rsrc)
#define HAVE_B64 1
// sc0 (GLC) load: bypass L1 allocation, serve+retain in L2.
// aux=1 -> sc0. voffset in bytes.
static __device__ __forceinline__ uint2 ld2_sc0(__amdgpu_buffer_rsrc_t rs, unsigned elem) {
    auto v = __builtin_amdgcn_raw_buffer_load_b64(rs, (int)(elem * 4u), 0, 1 /*sc0*/);
    return __builtin_bit_cast(uint2, v);
}
#else
#define HAVE_B64 0
#endif

// ---------------- Pass 0a: pack hashed tables to bf16 pairs ----------------
__global__ __launch_bounds__(256)
void ngp_pack(const float* __restrict__ tables)
{
    unsigned i = 6u * T_SIZE + (blockIdx.x * 256u + threadIdx.x) * 4u;
    const float4* s = (const float4*)(tables + (size_t)i * 2);
    float4 a = s[0], b = s[1];
    uint4 o;
    o.x = packbf(a.x, a.y);
    o.y = packbf(a.z, a.w);
    o.z = packbf(b.x, b.y);
    o.w = packbf(b.z, b.w);
    *(uint4*)(g_tbl + i) = o;
}

// ---------------- Pass 0b: dense duplicated-pair table ----------------
__global__ __launch_bounds__(256)
void ngp_dense(const float* __restrict__ tables)
{
    int idx = blockIdx.x * 256 + threadIdx.x;
    if (idx >= DP_TOTAL) return;
    int lvl = 0;
#pragma unroll
    for (int l = 1; l < 6; ++l) if (idx >= DP_OFF[l]) lvl = l;
    int loc = idx - DP_OFF[lvl];
    unsigned rp1 = (16u << lvl) + 1u;
    unsigned cy = (unsigned)loc / rp1;
    unsigned cx = (unsigned)loc - cy * rp1;
    const float2* t2 = (const float2*)tables + (size_t)lvl * T_SIZE;
    float2 a = t2[cy * rp1 + cx];
    unsigned cx1 = (cx + 1u < rp1) ? cx + 1u : cx;
    float2 b = t2[cy * rp1 + cx1];
    g_dp[idx] = make_uint2(packbf(a.x, a.y), packbf(b.x, b.y));
}

// ---------------- Pass 1: level-major hashgrid encode ----------------
// blockIdx = lvl * bpl + blk; 1024 points/block, 4 points/thread.
__global__ __launch_bounds__(256)
void ngp_encode(const float* __restrict__ uv, int npts, int bpl)
{
    const int bid = blockIdx.x;
    const int lvl = bid / bpl;
    const int blk = bid - lvl * bpl;
    const int base = (blk << 10) + (threadIdx.x << 2);
    if (base >= npts) return;

    const unsigned res = 16u << lvl;
    const float fres = (float)res;
    const unsigned mask = T_SIZE - 1u;

    // uv for 4 consecutive points.
    const float4* u4 = (const float4*)(uv + (size_t)base * 2);
    float4 ua = u4[0], ub = u4[1];
    float pxa[4] = {ua.x, ua.z, ub.x, ub.z};
    float pya[4] = {ua.y, ua.w, ub.y, ub.w};

    float wx[4], wy[4];
    unsigned v00[4], v10[4], v01[4], v11[4];   // packed bf16 corner values

    if (lvl < 6) {
        // ---- dense: pair table, 2 loads/pt (small, L1-friendly: plain loads) ----
        const unsigned rp1 = res + 1u;
        const uint2* __restrict__ dp = g_dp + DP_OFF[lvl];
        unsigned i0[4];
#pragma unroll
        for (int u = 0; u < 4; ++u) {
            float px = pxa[u] * fres, py = pya[u] * fres;
            float fx = floorf(px), fy = floorf(py);
            wx[u] = px - fx; wy[u] = py - fy;
            unsigned cx = (unsigned)fx, cy = (unsigned)fy;
            i0[u] = cy * rp1 + cx;
        }
        uint2 q0[4], q1[4];
#pragma unroll
        for (int u = 0; u < 4; ++u) {
            q0[u] = dp[i0[u]];
            q1[u] = dp[i0[u] + rp1];
        }
        __builtin_amdgcn_sched_barrier(0);
#pragma unroll
        for (int u = 0; u < 4; ++u) {
            v00[u] = q0[u].x; v10[u] = q0[u].y;
            v01[u] = q1[u].x; v11[u] = q1[u].y;
        }
    } else {
        // ---- hashed: even-x pair loads via xor-adjacency, sc0 (L1-bypass) ----
        const unsigned* __restrict__ tl = g_tbl + (size_t)lvl * T_SIZE;
#if HAVE_B64
        __amdgpu_buffer_rsrc_t rs = __builtin_amdgcn_make_buffer_rsrc(
            (void*)tl, (short)0 /*stride*/, (int)(T_SIZE * 4u) /*bytes*/, 0x00020000 /*raw dword*/);
#endif
        unsigned p00[4], p01[4], p10[4], p11[4], oddb[4], c0b[4];
#pragma unroll
        for (int u = 0; u < 4; ++u) {
            float px = pxa[u] * fres, py = pya[u] * fres;
            float fx = floorf(px), fy = floorf(py);
            wx[u] = px - fx; wy[u] = py - fy;
            unsigned cx = (unsigned)fx, cy = (unsigned)fy;
            unsigned odd = cx & 1u;
            unsigned cxe = cx & ~1u;
            unsigned cxn = (cx + 1u) & ~1u;          // next even coord (== cxe when cx even; masked off)
            unsigned hy0 = cy * HASH_Y, hy1 = hy0 + HASH_Y;
            p00[u] = ((cxe ^ hy0) & mask) & ~1u;
            p01[u] = ((cxe ^ hy1) & mask) & ~1u;
            p10[u] = ((cxn ^ hy0) & mask) & ~1u;
            p11[u] = ((cxn ^ hy1) & mask) & ~1u;
            oddb[u] = odd;
            c0b[u] = cy & 1u;
        }
        // Unconditional pair-0 loads (8), then exec-masked pair-1 loads
        // (odd-cx lanes only). All via sc0 -> no L1 line-fill slots consumed.
        uint2 q00[4], q01[4], r10[4], r11[4];
#pragma unroll
        for (int u = 0; u < 4; ++u) {
#if HAVE_B64
            q00[u] = ld2_sc0(rs, p00[u]);
            q01[u] = ld2_sc0(rs, p01[u]);
#else
            q00[u] = *(const uint2*)(tl + p00[u]);
            q01[u] = *(const uint2*)(tl + p01[u]);
#endif
            r10[u] = make_uint2(0u, 0u);
            r11[u] = make_uint2(0u, 0u);
        }
#pragma unroll
        for (int u = 0; u < 4; ++u) {
            if (oddb[u]) {
#if HAVE_B64
                r10[u] = ld2_sc0(rs, p10[u]);
                r11[u] = ld2_sc0(rs, p11[u]);
#else
                r10[u] = *(const uint2*)(tl + p10[u]);
                r11[u] = *(const uint2*)(tl + p11[u]);
#endif
            }
        }
        __builtin_amdgcn_sched_barrier(0);
        // Merge: slot(coord c) has bit0 = parity(c)^parity(hy); corner cxe is
        // at p + (cy&1)-dependent lane; for odd cx the right corner comes from
        // the pair-1 load.
#pragma unroll
        for (int u = 0; u < 4; ++u) {
            unsigned c0 = c0b[u], od = oddb[u];
            unsigned sL0 = c0 ^ od;
            unsigned c1 = c0 ^ 1u;
            unsigned sL1 = c1 ^ od;
            uint2 h10 = od ? r10[u] : q00[u];
            uint2 h11 = od ? r11[u] : q01[u];
            v00[u] = sL0 ? q00[u].y : q00[u].x;
            v10[u] = sL0 ? h10.x   : h10.y;      // index sL0^1
            v01[u] = sL1 ? q01[u].y : q01[u].x;
            v11[u] = sL1 ? h11.x   : h11.y;      // index sL1^1
        }
    }

    // ---- bilinear interp + pack ----
    unsigned pk[4];
#pragma unroll
    for (int u = 0; u < 4; ++u) {
        float w00 = (1.f - wx[u]) * (1.f - wy[u]);
        float w01 = (1.f - wx[u]) * wy[u];
        float w10 = wx[u] * (1.f - wy[u]);
        float w11 = wx[u] * wy[u];
        float g0 = w00 * bflo(v00[u]) + w01 * bflo(v01[u]) + w10 * bflo(v10[u]) + w11 * bflo(v11[u]);
        float g1 = w00 * bfhi(v00[u]) + w01 * bfhi(v01[u]) + w10 * bfhi(v10[u]) + w11 * bfhi(v11[u]);
        pk[u] = packbf(g0, g1);
    }
    *(uint4*)(g_feat + (size_t)lvl * npts + base) = make_uint4(pk[0], pk[1], pk[2], pk[3]);
}

// ---------------- Pass 2: fused MLP 32->128->128->3 (round-4 verified) ----------------
__global__ __launch_bounds__(256, 2)
void ngp_mlp(const float* __restrict__ w1, const float* __restrict__ b1,
             const float* __restrict__ w2, const float* __restrict__ b2,
             const float* __restrict__ w3, const float* __restrict__ b3,
             float* __restrict__ out, int npts)
{
    __shared__ __align__(16) unsigned short w2T[128 * 136];
    __shared__ __align__(16) unsigned short hbuf[4 * 16 * 136];
    __shared__ float b1s[128], b2s[128];

    const int tid = threadIdx.x;
    for (int e = tid; e < 128 * 128; e += 256) {        // w2 is [in][out]; store w2T[out][in]
        int i = e >> 7, o = e & 127;
        w2T[o * 136 + i] = f2bf(w2[e]);
    }
    if (tid < 128) { b1s[tid] = b1[tid]; b2s[tid] = b2[tid]; }
    __syncthreads();

    const int lane = tid & 63;
    const int wv = tid >> 6;
    const int lanelo = lane & 15;
    const int quad = lane >> 4;

    u16x8 a1[8];
#pragma unroll
    for (int mt = 0; mt < 8; ++mt)
#pragma unroll
        for (int j = 0; j < 8; ++j)
            a1[mt][j] = f2bf(w1[(quad * 8 + j) * 128 + mt * 16 + lanelo]);  // w1[k][m]

    u16x8 a3[4];
#pragma unroll
    for (int ks = 0; ks < 4; ++ks)
#pragma unroll
        for (int j = 0; j < 8; ++j) {
            int k = ks * 32 + quad * 8 + j;
            a3[ks][j] = (lanelo < 3) ? f2bf(w3[k * 3 + lanelo]) : (unsigned short)0;  // w3[k][m]
        }
    float b3r0 = b3[0], b3r1 = b3[1], b3r2 = b3[2];

    const int NT = npts >> 4;                 // 16-point tiles
    const int nwaves = gridDim.x * 4;
    const int gwave = blockIdx.x * 4 + wv;
    const int niter = (NT + nwaves - 1) / nwaves;   // uniform trip count (syncthreads-safe)

    unsigned short* hp = hbuf + (wv * 16 + lanelo) * 136;   // this lane's point-row
    const int lvlbase = quad << 2;            // this lane's 4 levels

    unsigned c0 = 0, c1 = 0, c2 = 0, c3 = 0;
    if (gwave < NT) {
        int pt0 = (gwave << 4) + lanelo;
        c0 = g_feat[(size_t)(lvlbase + 0) * npts + pt0];
        c1 = g_feat[(size_t)(lvlbase + 1) * npts + pt0];
        c2 = g_feat[(size_t)(lvlbase + 2) * npts + pt0];
        c3 = g_feat[(size_t)(lvlbase + 3) * npts + pt0];
    }

    for (int it = 0; it < niter; ++it) {
        int tile = gwave + it * nwaves;
        bool act = tile < NT;
        int pt = (tile << 4) + lanelo;

        if (act) {
            u16x8 xb;
            xb[0] = (unsigned short)(c0 & 0xffffu); xb[1] = (unsigned short)(c0 >> 16);
            xb[2] = (unsigned short)(c1 & 0xffffu); xb[3] = (unsigned short)(c1 >> 16);
            xb[4] = (unsigned short)(c2 & 0xffffu); xb[5] = (unsigned short)(c2 >> 16);
            xb[6] = (unsigned short)(c3 & 0xffffu); xb[7] = (unsigned short)(c3 >> 16);

            int tn = tile + nwaves;
            if (tn < NT) {
                int ptn = (tn << 4) + lanelo;
                c0 = g_feat[(size_t)(lvlbase + 0) * npts + ptn];
                c1 = g_feat[(size_t)(lvlbase + 1) * npts + ptn];
                c2 = g_feat[(size_t)(lvlbase + 2) * npts + ptn];
                c3 = g_feat[(size_t)(lvlbase + 3) * npts + ptn];
            }

            f32x4 z = {0.f, 0.f, 0.f, 0.f};
            f32x4 d[8];
#pragma unroll
            for (int mt = 0; mt < 8; ++mt) d[mt] = mfma16(a1[mt], xb, z);
#pragma unroll
            for (int mt = 0; mt < 8; ++mt) {
                u16x4 pk;
#pragma unroll
                for (int r = 0; r < 4; ++r) {
                    float hv = d[mt][r] + b1s[mt * 16 + quad * 4 + r];
                    pk[r] = f2bf(fmaxf(hv, 0.f));
                }
                *(u16x4*)(hp + mt * 16 + quad * 4) = pk;
            }
        }
        __syncthreads();
        if (act) {
            f32x4 z = {0.f, 0.f, 0.f, 0.f};
            f32x4 e[8];
#pragma unroll
            for (int mt = 0; mt < 8; ++mt) e[mt] = z;
#pragma unroll
            for (int ks = 0; ks < 4; ++ks) {
                u16x8 bb = *(const u16x8*)(hp + ks * 32 + quad * 8);   // h1[pt][k..k+7]
#pragma unroll
                for (int mt = 0; mt < 8; ++mt) {
                    u16x8 aa = *(const u16x8*)(w2T + (mt * 16 + lanelo) * 136 + ks * 32 + quad * 8);
                    e[mt] = mfma16(aa, bb, e[mt]);
                }
            }
#pragma unroll
            for (int mt = 0; mt < 8; ++mt) {
                u16x4 pk;
#pragma unroll
                for (int r = 0; r < 4; ++r) {
                    float hv = e[mt][r] + b2s[mt * 16 + quad * 4 + r];
                    pk[r] = f2bf(fmaxf(hv, 0.f));
                }
                *(u16x4*)(hp + mt * 16 + quad * 4) = pk;
            }
        }
        __syncthreads();
        if (act) {
            f32x4 o3 = {0.f, 0.f, 0.f, 0.f};
#pragma unroll
            for (int ks = 0; ks < 4; ++ks) {
                u16x8 bb = *(const u16x8*)(hp + ks * 32 + quad * 8);
                o3 = mfma16(a3[ks], bb, o3);
            }
            if (quad == 0) {   // D rows quad*4+r -> rows 0..2 live in quad 0
                float* op = out + (size_t)pt * 3;
                op[0] = 1.f / (1.f + expf(-(o3[0] + b3r0)));
                op[1] = 1.f / (1.f + expf(-(o3[1] + b3r1)));
                op[2] = 1.f / (1.f + expf(-(o3[2] + b3r2)));
            }
        }
    }
}

extern "C" void kernel_launch(void* const* d_in, const int* in_sizes, int n_in,
                              void* d_out, int out_size, void* d_ws, size_t ws_size,
                              hipStream_t stream) {
    const float* uv     = (const float*)d_in[0];
    const float* tables = (const float*)d_in[1];
    const float* w1     = (const float*)d_in[2];
    const float* b1     = (const float*)d_in[3];
    const float* w2     = (const float*)d_in[4];
    const float* b2     = (const float*)d_in[5];
    const float* w3     = (const float*)d_in[6];
    const float* b3     = (const float*)d_in[7];
    float* out = (float*)d_out;
    int npts = in_sizes[0] / 2;          // uv is [N,2]

    // Pass 0a: bf16-pack hashed levels 6..15 (10M entries, 4/thread).
    hipLaunchKernelGGL(ngp_pack, dim3((10u * T_SIZE) / 1024), dim3(256), 0, stream,
                       tables);
    // Pass 0b: dense duplicated-pair table (351462 entries).
    hipLaunchKernelGGL(ngp_dense, dim3((DP_TOTAL + 255) / 256), dim3(256), 0, stream,
                       tables);

    // Pass 1: level-major encode. bpl blocks of 1024 points per level.
    int bpl = (npts + 1023) >> 10;
    hipLaunchKernelGGL(ngp_encode, dim3(NLVL * bpl), dim3(256), 0, stream,
                       uv, npts, bpl);

    // Pass 2: fused MLP. 2048 blocks x 4 waves = 8192 wave-slots.
    hipLaunchKernelGGL(ngp_mlp, dim3(2048), dim3(256), 0, stream,
                       w1, b1, w2, b2, w3, b3, out, npts);
}

// Round 9
// 485.607 us; speedup vs baseline: 1.0878x; 1.0266x over previous
//
#include <hip/hip_runtime.h>

// Instant-NGP 2D hashgrid (L=16, T=2^20, F=2, N_MIN=16, b=2) + MLP 32->128->128->3.
//
// Four-kernel structure:
//   Pass 0a (ngp_pack): hashed levels 6..15 f32[T][2] -> packed bf16 u32[T].
//   Pass 0b (ngp_dense): dense levels 0..5 -> duplicated-pair table (2.8 MiB).
//   Pass 1 (ngp_encode): XCD-PINNED level scheduling (this round's delta).
//     History: r4 216us (16-deep batch), r5 223us (32-deep, occupancy halved,
//     rate flat => not latency-depth), r6 205us (-34% requests -> -5% => not
//     request-count; x-corner pairs already shared lines), r8 205us (sc0
//     L1-bypass neutral => not L1-MSHR). Invariant: ~2 distinct-line fetches
//     per point-level; FETCH 385MB => per-XCD L2 hit ~70% because the
//     dispatch window spans ~1.7 levels (~8MB) vs 4MiB L2, replicated on
//     all 8 XCDs. Remaining lever: average beyond-L1 latency = L2 hit rate.
//     Fix: blockIdx%8 -> XCD round-robin; schedule hashed levels 6..15 as
//     40 quarter-levels, XCD x gets items 5x..5x+4 in slot order => each
//     XCD's L2 holds exactly ONE 4MiB table at a time. Dense levels run as
//     a prefix grid padded to %8 so alignment holds.
//     NO nontemporal (r3: kills L2 retention), NO sc0 (r8: neutral).
//   Pass 2 (ngp_mlp): round-4-verified fused MLP, byte-identical.
//
// mfma_f32_16x16x32_bf16 layouts (HW-verified per guide):
//   A[m][k]: m = lane&15, k = (lane>>4)*8 + j   (8 bf16 / lane)
//   B[k][n]: n = lane&15, k = (lane>>4)*8 + j
//   D[m][n]: n = lane&15, m = (lane>>4)*4 + r   (4 f32 / lane)

#define T_SIZE  (1u << 20)
#define HASH_Y  2654435761u
#define NLVL    16
#define MAXPTS  (1u << 20)
#define DP_TOTAL 351462   // sum of (16*2^l+1)^2 for l=0..5

typedef __bf16 bf16x8 __attribute__((ext_vector_type(8)));
typedef float f32x4 __attribute__((ext_vector_type(4)));
typedef unsigned short u16x8 __attribute__((ext_vector_type(8)));
typedef unsigned short u16x4 __attribute__((ext_vector_type(4)));

__constant__ int DP_OFF[7] = {0, 289, 1378, 5603, 22244, 88293, DP_TOTAL};

// packed-bf16 hashed tables (levels 6..15 used) + dense pair table + features.
__device__ unsigned int g_tbl[NLVL * T_SIZE];
__device__ uint2        g_dp[DP_TOTAL];
__device__ unsigned int g_feat[NLVL * MAXPTS];

static __device__ __forceinline__ unsigned short f2bf(float f) {
    union { float f; unsigned u; } v; v.f = f;
    unsigned u = v.u;
    u += 0x7fffu + ((u >> 16) & 1u);   // round-to-nearest-even
    return (unsigned short)(u >> 16);
}

static __device__ __forceinline__ unsigned packbf(float a, float b) {
    return (unsigned)f2bf(a) | ((unsigned)f2bf(b) << 16);
}

static __device__ __forceinline__ float bflo(unsigned p) {
    union { unsigned u; float f; } v; v.u = p << 16; return v.f;
}
static __device__ __forceinline__ float bfhi(unsigned p) {
    union { unsigned u; float f; } v; v.u = p & 0xffff0000u; return v.f;
}

static __device__ __forceinline__ f32x4 mfma16(u16x8 a, u16x8 b, f32x4 c) {
    return __builtin_amdgcn_mfma_f32_16x16x32_bf16(
        __builtin_bit_cast(bf16x8, a), __builtin_bit_cast(bf16x8, b), c, 0, 0, 0);
}

// ---------------- Pass 0a: pack hashed tables to bf16 pairs ----------------
__global__ __launch_bounds__(256)
void ngp_pack(const float* __restrict__ tables)
{
    unsigned i = 6u * T_SIZE + (blockIdx.x * 256u + threadIdx.x) * 4u;
    const float4* s = (const float4*)(tables + (size_t)i * 2);
    float4 a = s[0], b = s[1];
    uint4 o;
    o.x = packbf(a.x, a.y);
    o.y = packbf(a.z, a.w);
    o.z = packbf(b.x, b.y);
    o.w = packbf(b.z, b.w);
    *(uint4*)(g_tbl + i) = o;
}

// ---------------- Pass 0b: dense duplicated-pair table ----------------
__global__ __launch_bounds__(256)
void ngp_dense(const float* __restrict__ tables)
{
    int idx = blockIdx.x * 256 + threadIdx.x;
    if (idx >= DP_TOTAL) return;
    int lvl = 0;
#pragma unroll
    for (int l = 1; l < 6; ++l) if (idx >= DP_OFF[l]) lvl = l;
    int loc = idx - DP_OFF[lvl];
    unsigned rp1 = (16u << lvl) + 1u;
    unsigned cy = (unsigned)loc / rp1;
    unsigned cx = (unsigned)loc - cy * rp1;
    const float2* t2 = (const float2*)tables + (size_t)lvl * T_SIZE;
    float2 a = t2[cy * rp1 + cx];
    unsigned cx1 = (cx + 1u < rp1) ? cx + 1u : cx;
    float2 b = t2[cy * rp1 + cx1];
    g_dp[idx] = make_uint2(packbf(a.x, a.y), packbf(b.x, b.y));
}

// ---------------- Pass 1: XCD-pinned level-scheduled encode ----------------
// Grid = [dense prefix: nblk_d blocks (6*bpl used, padded to %8)]
//      + [hashed: 40*bq blocks].
// Hashed decode: h = bid - nblk_d; xcd = h&7 (== bid&7 since nblk_d%8==0);
//   slot = (h>>3)/bq; item = xcd*5+slot in 0..39; lvl = 6+item/4;
//   blk = (item&3)*bq + (h>>3)%bq.  Each XCD runs its 5 items in slot order
//   -> one 4MiB table resident in its private L2 at a time.
__global__ __launch_bounds__(256)
void ngp_encode(const float* __restrict__ uv, int npts, int bpl, int bq, int nblk_d)
{
    const int bid = blockIdx.x;
    int lvl, blk;
    if (bid < nblk_d) {
        lvl = bid / bpl;
        if (lvl >= 6) return;            // %8 padding blocks
        blk = bid - lvl * bpl;
    } else {
        int h = bid - nblk_d;
        int xcd = h & 7;
        int rest = h >> 3;
        int slot = rest / bq;
        int sub  = rest - slot * bq;
        int item = xcd * 5 + slot;       // 0..39, bijective
        lvl = 6 + (item >> 2);
        blk = (item & 3) * bq + sub;     // quarter*bq + sub
    }
    const int base = (blk << 10) + (threadIdx.x << 2);
    if (base >= npts) return;

    const unsigned res = 16u << lvl;
    const float fres = (float)res;
    const unsigned mask = T_SIZE - 1u;

    // uv for 4 consecutive points.
    const float4* u4 = (const float4*)(uv + (size_t)base * 2);
    float4 ua = u4[0], ub = u4[1];
    float pxa[4] = {ua.x, ua.z, ub.x, ub.z};
    float pya[4] = {ua.y, ua.w, ub.y, ub.w};

    float wx[4], wy[4];
    unsigned v00[4], v10[4], v01[4], v11[4];   // packed bf16 corner values

    if (lvl < 6) {
        // ---- dense: pair table, 2 loads/pt ----
        const unsigned rp1 = res + 1u;
        const uint2* __restrict__ dp = g_dp + DP_OFF[lvl];
        unsigned i0[4];
#pragma unroll
        for (int u = 0; u < 4; ++u) {
            float px = pxa[u] * fres, py = pya[u] * fres;
            float fx = floorf(px), fy = floorf(py);
            wx[u] = px - fx; wy[u] = py - fy;
            unsigned cx = (unsigned)fx, cy = (unsigned)fy;
            i0[u] = cy * rp1 + cx;
        }
        uint2 q0[4], q1[4];
#pragma unroll
        for (int u = 0; u < 4; ++u) {
            q0[u] = dp[i0[u]];
            q1[u] = dp[i0[u] + rp1];
        }
        __builtin_amdgcn_sched_barrier(0);
#pragma unroll
        for (int u = 0; u < 4; ++u) {
            v00[u] = q0[u].x; v10[u] = q0[u].y;
            v01[u] = q1[u].x; v11[u] = q1[u].y;
        }
    } else {
        // ---- hashed: even-x pair loads via xor-adjacency ----
        const unsigned* __restrict__ tl = g_tbl + (size_t)lvl * T_SIZE;
        unsigned p00[4], p01[4], p10[4], p11[4], oddb[4], c0b[4];
#pragma unroll
        for (int u = 0; u < 4; ++u) {
            float px = pxa[u] * fres, py = pya[u] * fres;
            float fx = floorf(px), fy = floorf(py);
            wx[u] = px - fx; wy[u] = py - fy;
            unsigned cx = (unsigned)fx, cy = (unsigned)fy;
            unsigned odd = cx & 1u;
            unsigned cxe = cx & ~1u;
            unsigned cxn = (cx + 1u) & ~1u;          // next even coord (masked off when even)
            unsigned hy0 = cy * HASH_Y, hy1 = hy0 + HASH_Y;
            p00[u] = ((cxe ^ hy0) & mask) & ~1u;
            p01[u] = ((cxe ^ hy1) & mask) & ~1u;
            p10[u] = ((cxn ^ hy0) & mask) & ~1u;
            p11[u] = ((cxn ^ hy1) & mask) & ~1u;
            oddb[u] = odd;
            c0b[u] = cy & 1u;
        }
        // Unconditional pair-0 loads (8), then exec-masked pair-1 loads.
        uint2 q00[4], q01[4], r10[4], r11[4];
#pragma unroll
        for (int u = 0; u < 4; ++u) {
            q00[u] = *(const uint2*)(tl + p00[u]);
            q01[u] = *(const uint2*)(tl + p01[u]);
            r10[u] = make_uint2(0u, 0u);
            r11[u] = make_uint2(0u, 0u);
        }
#pragma unroll
        for (int u = 0; u < 4; ++u) {
            if (oddb[u]) {
                r10[u] = *(const uint2*)(tl + p10[u]);
                r11[u] = *(const uint2*)(tl + p11[u]);
            }
        }
        __builtin_amdgcn_sched_barrier(0);
        // Merge: slot(coord c) bit0 = parity(c)^parity(hy).
#pragma unroll
        for (int u = 0; u < 4; ++u) {
            unsigned c0 = c0b[u], od = oddb[u];
            unsigned sL0 = c0 ^ od;
            unsigned c1 = c0 ^ 1u;
            unsigned sL1 = c1 ^ od;
            uint2 h10 = od ? r10[u] : q00[u];
            uint2 h11 = od ? r11[u] : q01[u];
            v00[u] = sL0 ? q00[u].y : q00[u].x;
            v10[u] = sL0 ? h10.x   : h10.y;      // index sL0^1
            v01[u] = sL1 ? q01[u].y : q01[u].x;
            v11[u] = sL1 ? h11.x   : h11.y;      // index sL1^1
        }
    }

    // ---- bilinear interp + pack ----
    unsigned pk[4];
#pragma unroll
    for (int u = 0; u < 4; ++u) {
        float w00 = (1.f - wx[u]) * (1.f - wy[u]);
        float w01 = (1.f - wx[u]) * wy[u];
        float w10 = wx[u] * (1.f - wy[u]);
        float w11 = wx[u] * wy[u];
        float g0 = w00 * bflo(v00[u]) + w01 * bflo(v01[u]) + w10 * bflo(v10[u]) + w11 * bflo(v11[u]);
        float g1 = w00 * bfhi(v00[u]) + w01 * bfhi(v01[u]) + w10 * bfhi(v10[u]) + w11 * bfhi(v11[u]);
        pk[u] = packbf(g0, g1);
    }
    *(uint4*)(g_feat + (size_t)lvl * npts + base) = make_uint4(pk[0], pk[1], pk[2], pk[3]);
}

// ---------------- Pass 2: fused MLP 32->128->128->3 (round-4 verified) ----------------
__global__ __launch_bounds__(256, 2)
void ngp_mlp(const float* __restrict__ w1, const float* __restrict__ b1,
             const float* __restrict__ w2, const float* __restrict__ b2,
             const float* __restrict__ w3, const float* __restrict__ b3,
             float* __restrict__ out, int npts)
{
    __shared__ __align__(16) unsigned short w2T[128 * 136];
    __shared__ __align__(16) unsigned short hbuf[4 * 16 * 136];
    __shared__ float b1s[128], b2s[128];

    const int tid = threadIdx.x;
    for (int e = tid; e < 128 * 128; e += 256) {        // w2 is [in][out]; store w2T[out][in]
        int i = e >> 7, o = e & 127;
        w2T[o * 136 + i] = f2bf(w2[e]);
    }
    if (tid < 128) { b1s[tid] = b1[tid]; b2s[tid] = b2[tid]; }
    __syncthreads();

    const int lane = tid & 63;
    const int wv = tid >> 6;
    const int lanelo = lane & 15;
    const int quad = lane >> 4;

    u16x8 a1[8];
#pragma unroll
    for (int mt = 0; mt < 8; ++mt)
#pragma unroll
        for (int j = 0; j < 8; ++j)
            a1[mt][j] = f2bf(w1[(quad * 8 + j) * 128 + mt * 16 + lanelo]);  // w1[k][m]

    u16x8 a3[4];
#pragma unroll
    for (int ks = 0; ks < 4; ++ks)
#pragma unroll
        for (int j = 0; j < 8; ++j) {
            int k = ks * 32 + quad * 8 + j;
            a3[ks][j] = (lanelo < 3) ? f2bf(w3[k * 3 + lanelo]) : (unsigned short)0;  // w3[k][m]
        }
    float b3r0 = b3[0], b3r1 = b3[1], b3r2 = b3[2];

    const int NT = npts >> 4;                 // 16-point tiles
    const int nwaves = gridDim.x * 4;
    const int gwave = blockIdx.x * 4 + wv;
    const int niter = (NT + nwaves - 1) / nwaves;   // uniform trip count (syncthreads-safe)

    unsigned short* hp = hbuf + (wv * 16 + lanelo) * 136;   // this lane's point-row
    const int lvlbase = quad << 2;            // this lane's 4 levels

    unsigned c0 = 0, c1 = 0, c2 = 0, c3 = 0;
    if (gwave < NT) {
        int pt0 = (gwave << 4) + lanelo;
        c0 = g_feat[(size_t)(lvlbase + 0) * npts + pt0];
        c1 = g_feat[(size_t)(lvlbase + 1) * npts + pt0];
        c2 = g_feat[(size_t)(lvlbase + 2) * npts + pt0];
        c3 = g_feat[(size_t)(lvlbase + 3) * npts + pt0];
    }

    for (int it = 0; it < niter; ++it) {
        int tile = gwave + it * nwaves;
        bool act = tile < NT;
        int pt = (tile << 4) + lanelo;

        if (act) {
            u16x8 xb;
            xb[0] = (unsigned short)(c0 & 0xffffu); xb[1] = (unsigned short)(c0 >> 16);
            xb[2] = (unsigned short)(c1 & 0xffffu); xb[3] = (unsigned short)(c1 >> 16);
            xb[4] = (unsigned short)(c2 & 0xffffu); xb[5] = (unsigned short)(c2 >> 16);
            xb[6] = (unsigned short)(c3 & 0xffffu); xb[7] = (unsigned short)(c3 >> 16);

            int tn = tile + nwaves;
            if (tn < NT) {
                int ptn = (tn << 4) + lanelo;
                c0 = g_feat[(size_t)(lvlbase + 0) * npts + ptn];
                c1 = g_feat[(size_t)(lvlbase + 1) * npts + ptn];
                c2 = g_feat[(size_t)(lvlbase + 2) * npts + ptn];
                c3 = g_feat[(size_t)(lvlbase + 3) * npts + ptn];
            }

            f32x4 z = {0.f, 0.f, 0.f, 0.f};
            f32x4 d[8];
#pragma unroll
            for (int mt = 0; mt < 8; ++mt) d[mt] = mfma16(a1[mt], xb, z);
#pragma unroll
            for (int mt = 0; mt < 8; ++mt) {
                u16x4 pk;
#pragma unroll
                for (int r = 0; r < 4; ++r) {
                    float hv = d[mt][r] + b1s[mt * 16 + quad * 4 + r];
                    pk[r] = f2bf(fmaxf(hv, 0.f));
                }
                *(u16x4*)(hp + mt * 16 + quad * 4) = pk;
            }
        }
        __syncthreads();
        if (act) {
            f32x4 z = {0.f, 0.f, 0.f, 0.f};
            f32x4 e[8];
#pragma unroll
            for (int mt = 0; mt < 8; ++mt) e[mt] = z;
#pragma unroll
            for (int ks = 0; ks < 4; ++ks) {
                u16x8 bb = *(const u16x8*)(hp + ks * 32 + quad * 8);   // h1[pt][k..k+7]
#pragma unroll
                for (int mt = 0; mt < 8; ++mt) {
                    u16x8 aa = *(const u16x8*)(w2T + (mt * 16 + lanelo) * 136 + ks * 32 + quad * 8);
                    e[mt] = mfma16(aa, bb, e[mt]);
                }
            }
#pragma unroll
            for (int mt = 0; mt < 8; ++mt) {
                u16x4 pk;
#pragma unroll
                for (int r = 0; r < 4; ++r) {
                    float hv = e[mt][r] + b2s[mt * 16 + quad * 4 + r];
                    pk[r] = f2bf(fmaxf(hv, 0.f));
                }
                *(u16x4*)(hp + mt * 16 + quad * 4) = pk;
            }
        }
        __syncthreads();
        if (act) {
            f32x4 o3 = {0.f, 0.f, 0.f, 0.f};
#pragma unroll
            for (int ks = 0; ks < 4; ++ks) {
                u16x8 bb = *(const u16x8*)(hp + ks * 32 + quad * 8);
                o3 = mfma16(a3[ks], bb, o3);
            }
            if (quad == 0) {   // D rows quad*4+r -> rows 0..2 live in quad 0
                float* op = out + (size_t)pt * 3;
                op[0] = 1.f / (1.f + expf(-(o3[0] + b3r0)));
                op[1] = 1.f / (1.f + expf(-(o3[1] + b3r1)));
                op[2] = 1.f / (1.f + expf(-(o3[2] + b3r2)));
            }
        }
    }
}

extern "C" void kernel_launch(void* const* d_in, const int* in_sizes, int n_in,
                              void* d_out, int out_size, void* d_ws, size_t ws_size,
                              hipStream_t stream) {
    const float* uv     = (const float*)d_in[0];
    const float* tables = (const float*)d_in[1];
    const float* w1     = (const float*)d_in[2];
    const float* b1     = (const float*)d_in[3];
    const float* w2     = (const float*)d_in[4];
    const float* b2     = (const float*)d_in[5];
    const float* w3     = (const float*)d_in[6];
    const float* b3     = (const float*)d_in[7];
    float* out = (float*)d_out;
    int npts = in_sizes[0] / 2;          // uv is [N,2]

    // Pass 0a: bf16-pack hashed levels 6..15 (10M entries, 4/thread).
    hipLaunchKernelGGL(ngp_pack, dim3((10u * T_SIZE) / 1024), dim3(256), 0, stream,
                       tables);
    // Pass 0b: dense duplicated-pair table (351462 entries).
    hipLaunchKernelGGL(ngp_dense, dim3((DP_TOTAL + 255) / 256), dim3(256), 0, stream,
                       tables);

    // Pass 1: XCD-pinned level-scheduled encode.
    int bpl = (npts + 1023) >> 10;            // blocks per level (1024 pts/block)
    int bq  = (bpl + 3) >> 2;                 // blocks per quarter-level
    int nblk_d = (6 * bpl + 7) & ~7;          // dense prefix, padded to %8
    int nblk = nblk_d + 40 * bq;              // + 8 XCDs * 5 slots * bq
    hipLaunchKernelGGL(ngp_encode, dim3(nblk), dim3(256), 0, stream,
                       uv, npts, bpl, bq, nblk_d);

    // Pass 2: fused MLP. 2048 blocks x 4 waves = 8192 wave-slots.
    hipLaunchKernelGGL(ngp_mlp, dim3(2048), dim3(256), 0, stream,
                       w1, b1, w2, b2, w3, b3, out, npts);
}